// Round 8
// baseline (158.174 us; speedup 1.0000x reference)
//
#include <hip/hip_runtime.h>
#include <hip/hip_bf16.h>

#define DOUT 128
#define NEG 0.01f

__device__ __forceinline__ unsigned short f2bf(float f) {
    union { float f; unsigned int i; } c; c.f = f;
    unsigned int r = c.i + 0x7FFF + ((c.i >> 16) & 1);   // round-to-nearest-even
    return (unsigned short)(r >> 16);
}

// ---------------- fused: GEMM h = x@W+b (+ s_dst/s_src) | CSR offsets ----------------
// BM=32 (16KB LDS): 1563 gemm blocks -> ~6 blocks/CU (vs 3 at BM=64), halves
// the tail imbalance. NO unroll pragma / manual prefetch on the k-loop: full
// unroll spilled at VGPR=256 (R3 post-mortem: 600us, 1.5GB scratch traffic).
#define BM 32

__global__ __launch_bounds__(256)
void gemm_build(const float* __restrict__ x, const float* __restrict__ W,
                const float* __restrict__ b, const float* __restrict__ a_w,
                unsigned short* __restrict__ h, float* __restrict__ s_dst,
                float* __restrict__ s_src,
                const int* __restrict__ edge_dst, int* __restrict__ offsets,
                int N, int E, int gemmBlocks)
{
    const int tid = threadIdx.x;

    if (blockIdx.x >= gemmBlocks) {
        // ---- CSR offsets section ----
        int e = (blockIdx.x - gemmBlocks) * 256 + tid;
        if (e < E) {
            int d = edge_dst[e];
            int prev = (e == 0) ? -1 : edge_dst[e - 1];
            for (int n = prev + 1; n <= d; ++n) offsets[n] = e;
            if (e == E - 1)
                for (int n = d + 1; n <= N; ++n) offsets[n] = E;
        }
        return;
    }

    // ---- GEMM section ----
    __shared__ float Xs[BM][DOUT];   // 16 KB
    const int row0 = blockIdx.x * BM;

    // stage x tile: 32x128 floats = 1024 float4, 4 per thread, coalesced
#pragma unroll
    for (int i = 0; i < 4; ++i) {
        int q = i * 256 + tid;
        int r = q >> 5;
        int c = (q & 31) << 2;
        int gn = row0 + r;
        float4 v = make_float4(0.f, 0.f, 0.f, 0.f);
        if (gn < N) v = *(const float4*)&x[(size_t)gn * DOUT + c];
        *(float4*)&Xs[r][c] = v;
    }
    __syncthreads();

    const int dg = (tid & 31) << 2;     // dim base (4 dims)
    const int r0 = (tid >> 5) << 2;     // node base (4 nodes)

    float acc[4][4];
#pragma unroll
    for (int i = 0; i < 4; ++i)
#pragma unroll
        for (int j = 0; j < 4; ++j) acc[i][j] = 0.f;

    for (int k = 0; k < DOUT; k += 4) {
        float4 w0 = *(const float4*)&W[(size_t)(k + 0) * DOUT + dg];
        float4 w1 = *(const float4*)&W[(size_t)(k + 1) * DOUT + dg];
        float4 w2 = *(const float4*)&W[(size_t)(k + 2) * DOUT + dg];
        float4 w3 = *(const float4*)&W[(size_t)(k + 3) * DOUT + dg];
#pragma unroll
        for (int i = 0; i < 4; ++i) {
            float4 xq = *(float4*)&Xs[r0 + i][k];   // wave-broadcast (free)
            acc[i][0] += xq.x * w0.x + xq.y * w1.x + xq.z * w2.x + xq.w * w3.x;
            acc[i][1] += xq.x * w0.y + xq.y * w1.y + xq.z * w2.y + xq.w * w3.y;
            acc[i][2] += xq.x * w0.z + xq.y * w1.z + xq.z * w2.z + xq.w * w3.z;
            acc[i][3] += xq.x * w0.w + xq.y * w1.w + xq.z * w2.w + xq.w * w3.w;
        }
    }

    const float4 bb   = *(const float4*)&b[dg];
    const float4 aw_d = *(const float4*)&a_w[dg];
    const float4 aw_s = *(const float4*)&a_w[DOUT + dg];
#pragma unroll
    for (int i = 0; i < 4; ++i) {
        int gn = row0 + r0 + i;
        float4 o;
        o.x = acc[i][0] + bb.x;
        o.y = acc[i][1] + bb.y;
        o.z = acc[i][2] + bb.z;
        o.w = acc[i][3] + bb.w;
        if (gn < N) {
            ushort4 hb;
            hb.x = f2bf(o.x); hb.y = f2bf(o.y); hb.z = f2bf(o.z); hb.w = f2bf(o.w);
            *(ushort4*)&h[(size_t)gn * DOUT + dg] = hb;
        }
        float sd = o.x * aw_d.x + o.y * aw_d.y + o.z * aw_d.z + o.w * aw_d.w;
        float ss = o.x * aw_s.x + o.y * aw_s.y + o.z * aw_s.z + o.w * aw_s.w;
#pragma unroll
        for (int off = 16; off; off >>= 1) {
            sd += __shfl_xor(sd, off, 32);
            ss += __shfl_xor(ss, off, 32);
        }
        if ((tid & 31) == 0 && gn < N) { s_dst[gn] = sd; s_src[gn] = ss; }
    }
}

// ---------------- segment softmax + aggregation: 16-lane group per node ----------------
// Single fused softmax pass: logits ~ N(0,1) (s std ~0.7 by construction), so
// exp() without max-subtraction is safe in fp32 and mathematically identical.
// Pass 2 keeps 8 uint4 row-loads in flight per lane against L2/L3 latency.
#define GL 16      // lanes per group
#define KSLOT 4    // register slots -> 64 edges cached

__device__ __forceinline__ void fma8(unsigned int u0, unsigned int u1,
                                     unsigned int u2, unsigned int u3,
                                     float w, float* a) {
    union { unsigned int i; float f; } c;
    c.i = u0 << 16;         a[0] += w * c.f;
    c.i = u0 & 0xFFFF0000u; a[1] += w * c.f;
    c.i = u1 << 16;         a[2] += w * c.f;
    c.i = u1 & 0xFFFF0000u; a[3] += w * c.f;
    c.i = u2 << 16;         a[4] += w * c.f;
    c.i = u2 & 0xFFFF0000u; a[5] += w * c.f;
    c.i = u3 << 16;         a[6] += w * c.f;
    c.i = u3 & 0xFFFF0000u; a[7] += w * c.f;
}

__global__ __launch_bounds__(256)
void gat_agg(const int* __restrict__ edge_src, const int* __restrict__ offsets,
             const unsigned short* __restrict__ h, const float* __restrict__ s_src,
             const float* __restrict__ s_dst, const float* __restrict__ a_b,
             float* __restrict__ out, int N)
{
    const int lg16 = threadIdx.x & (GL - 1);            // lane within group
    const int n = blockIdx.x * 16 + (threadIdx.x >> 4); // node for this group
    const bool active = (n < N);

    int start = 0, end = 0;
    float sdn = 0.f;
    if (active) {
        start = offsets[n];
        end = offsets[n + 1];
        sdn = s_dst[n] + a_b[0];
    }
    const int deg = end - start;

    // ---- pass 1 (fused): exp weights into register slots + group sum ----
    float wr[KSLOT];
    int   sreg[KSLOT];
    float mysum = 0.f;
#pragma unroll
    for (int t = 0; t < KSLOT; ++t) {
        int i = lg16 + t * GL;
        wr[t] = 0.f; sreg[t] = 0;
        if (i < deg) {
            int s = edge_src[start + i];
            float lg = sdn + s_src[s];
            lg = lg >= 0.f ? lg : NEG * lg;
            float w = __expf(lg);
            sreg[t] = s; wr[t] = w;
            mysum += w;
        }
    }
    for (int i = lg16 + KSLOT * GL; i < deg; i += GL) {  // overflow (deg>64, ~never)
        float lg = sdn + s_src[edge_src[start + i]];
        lg = lg >= 0.f ? lg : NEG * lg;
        mysum += __expf(lg);
    }
#pragma unroll
    for (int o = 8; o; o >>= 1) mysum += __shfl_xor(mysum, o, GL);

    // ---- pass 2: gather rows; lane = 8 dims (16 lanes x 16B = 256B bf16 row) ----
    const uint4* __restrict__ h4 = (const uint4*)h;      // row stride = 16 uint4
    float a[8];
#pragma unroll
    for (int q = 0; q < 8; ++q) a[q] = 0.f;

    const int degc = deg < KSLOT * GL ? deg : KSLOT * GL;
#pragma unroll
    for (int t = 0; t < KSLOT; ++t) {
        const int base = t * GL;
        if (base >= degc) break;
        const int cnt = (degc - base) < GL ? (degc - base) : GL;
        const float wt = wr[t];
        const int   st = sreg[t];
        int j = 0;
        for (; j + 8 <= cnt; j += 8) {                   // 8 rows in flight
            float wj[8]; int sj[8]; uint4 vj[8];
#pragma unroll
            for (int q = 0; q < 8; ++q) {
                wj[q] = __shfl(wt, j + q, GL);
                sj[q] = __shfl(st, j + q, GL);
            }
#pragma unroll
            for (int q = 0; q < 8; ++q) vj[q] = h4[(size_t)sj[q] * 16 + lg16];
#pragma unroll
            for (int q = 0; q < 8; ++q) fma8(vj[q].x, vj[q].y, vj[q].z, vj[q].w, wj[q], a);
        }
        for (; j < cnt; ++j) {
            float w = __shfl(wt, j, GL); int s = __shfl(st, j, GL);
            uint4 v = h4[(size_t)s * 16 + lg16];
            fma8(v.x, v.y, v.z, v.w, w, a);
        }
    }
    for (int i = KSLOT * GL; i < deg; ++i) {             // overflow (uniform addr)
        int s = edge_src[start + i];
        float lgv = sdn + s_src[s];
        lgv = lgv >= 0.f ? lgv : NEG * lgv;
        float w = __expf(lgv);
        uint4 v = h4[(size_t)s * 16 + lg16];
        fma8(v.x, v.y, v.z, v.w, w, a);
    }

    if (active) {
        const float inv = 1.f / fmaxf(mysum, 1e-16f);
        float4 o0, o1;
        o0.x = a[0] * inv; o0.y = a[1] * inv; o0.z = a[2] * inv; o0.w = a[3] * inv;
        o1.x = a[4] * inv; o1.y = a[5] * inv; o1.z = a[6] * inv; o1.w = a[7] * inv;
        float4* op = (float4*)&out[(size_t)n * DOUT + lg16 * 8];
        op[0] = o0;
        op[1] = o1;
    }
}

extern "C" void kernel_launch(void* const* d_in, const int* in_sizes, int n_in,
                              void* d_out, int out_size, void* d_ws, size_t ws_size,
                              hipStream_t stream)
{
    const float* x        = (const float*)d_in[0];
    const int*   edge_src = (const int*)d_in[1];
    const int*   edge_dst = (const int*)d_in[2];
    const float* W        = (const float*)d_in[3];
    const float* b        = (const float*)d_in[4];
    const float* a_w      = (const float*)d_in[5];
    const float* a_b      = (const float*)d_in[6];
    const int N = in_sizes[0] / DOUT;
    const int E = in_sizes[1];
    float* out = (float*)d_out;

    char* ws = (char*)d_ws;
    unsigned short* h = (unsigned short*)ws;  ws += (size_t)N * DOUT * sizeof(unsigned short);
    float* s_dst   = (float*)ws;  ws += (size_t)N * sizeof(float);
    float* s_src   = (float*)ws;  ws += (size_t)N * sizeof(float);
    int*   offsets = (int*)ws;    ws += (size_t)(N + 1) * sizeof(int);

    const int gemmBlocks = (N + BM - 1) / BM;
    const int buildBlocks = (E + 255) / 256;
    gemm_build<<<gemmBlocks + buildBlocks, 256, 0, stream>>>(
        x, W, b, a_w, h, s_dst, s_src, edge_dst, offsets, N, E, gemmBlocks);
    gat_agg<<<(N + 15) / 16, 256, 0, stream>>>(edge_src, offsets, h, s_src, s_dst, a_b, out, N);
}

// Round 9
// 157.607 us; speedup vs baseline: 1.0036x; 1.0036x over previous
//
#include <hip/hip_runtime.h>
#include <hip/hip_bf16.h>

#define DOUT 128
#define NEG 0.01f

__device__ __forceinline__ unsigned short f2bf(float f) {
    union { float f; unsigned int i; } c; c.f = f;
    unsigned int r = c.i + 0x7FFF + ((c.i >> 16) & 1);   // round-to-nearest-even
    return (unsigned short)(r >> 16);
}

// ---------------- fused: GEMM h = x@W+b (+ s_dst/s_src) | CSR offsets ----------------
// BM=64, 8 nodes x 4 dims per thread (best FMA:W-load ratio tried; BM=32
// halved it and regressed — R8). W k-chunk prefetched one step ahead in
// registers so the vmcnt wait lands after 256 FMA-cycles, not immediately.
// #pragma unroll 1 pins the loop: full unroll spilled at VGPR=256 (R3: 600us).
#define BM 64

__global__ __launch_bounds__(256)
void gemm_build(const float* __restrict__ x, const float* __restrict__ W,
                const float* __restrict__ b, const float* __restrict__ a_w,
                unsigned short* __restrict__ h, float* __restrict__ s_dst,
                float* __restrict__ s_src,
                const int* __restrict__ edge_dst, int* __restrict__ offsets,
                int N, int E, int gemmBlocks)
{
    const int tid = threadIdx.x;

    if (blockIdx.x >= gemmBlocks) {
        // ---- CSR offsets section ----
        int e = (blockIdx.x - gemmBlocks) * 256 + tid;
        if (e < E) {
            int d = edge_dst[e];
            int prev = (e == 0) ? -1 : edge_dst[e - 1];
            for (int n = prev + 1; n <= d; ++n) offsets[n] = e;
            if (e == E - 1)
                for (int n = d + 1; n <= N; ++n) offsets[n] = E;
        }
        return;
    }

    // ---- GEMM section ----
    __shared__ float Xs[BM][DOUT];   // 32 KB
    const int row0 = blockIdx.x * BM;

    // stage x tile: 64x128 floats = 2048 float4, 8 per thread, coalesced
#pragma unroll
    for (int i = 0; i < 8; ++i) {
        int q = i * 256 + tid;
        int r = q >> 5;
        int c = (q & 31) << 2;
        int gn = row0 + r;
        float4 v = make_float4(0.f, 0.f, 0.f, 0.f);
        if (gn < N) v = *(const float4*)&x[(size_t)gn * DOUT + c];
        *(float4*)&Xs[r][c] = v;
    }
    __syncthreads();

    const int dg = (tid & 31) << 2;     // dim base (4 dims)
    const int r0 = (tid >> 5) << 3;     // node base (8 nodes)

    float acc[8][4];
#pragma unroll
    for (int i = 0; i < 8; ++i)
#pragma unroll
        for (int j = 0; j < 4; ++j) acc[i][j] = 0.f;

    // prefetch first W chunk
    float4 wc0 = *(const float4*)&W[(size_t)0 * DOUT + dg];
    float4 wc1 = *(const float4*)&W[(size_t)1 * DOUT + dg];
    float4 wc2 = *(const float4*)&W[(size_t)2 * DOUT + dg];
    float4 wc3 = *(const float4*)&W[(size_t)3 * DOUT + dg];

#pragma unroll 1
    for (int k = 0; k < DOUT; k += 4) {
        // issue next chunk's loads BEFORE consuming the current one
        float4 wn0, wn1, wn2, wn3;
        const int kn = (k + 4 < DOUT) ? k + 4 : k;   // last iter: reload (discarded)
        wn0 = *(const float4*)&W[(size_t)(kn + 0) * DOUT + dg];
        wn1 = *(const float4*)&W[(size_t)(kn + 1) * DOUT + dg];
        wn2 = *(const float4*)&W[(size_t)(kn + 2) * DOUT + dg];
        wn3 = *(const float4*)&W[(size_t)(kn + 3) * DOUT + dg];
#pragma unroll
        for (int i = 0; i < 8; ++i) {
            float4 xq = *(float4*)&Xs[r0 + i][k];   // wave-broadcast (free)
            acc[i][0] += xq.x * wc0.x + xq.y * wc1.x + xq.z * wc2.x + xq.w * wc3.x;
            acc[i][1] += xq.x * wc0.y + xq.y * wc1.y + xq.z * wc2.y + xq.w * wc3.y;
            acc[i][2] += xq.x * wc0.z + xq.y * wc1.z + xq.z * wc2.z + xq.w * wc3.z;
            acc[i][3] += xq.x * wc0.w + xq.y * wc1.w + xq.z * wc2.w + xq.w * wc3.w;
        }
        wc0 = wn0; wc1 = wn1; wc2 = wn2; wc3 = wn3;
    }

    const float4 bb   = *(const float4*)&b[dg];
    const float4 aw_d = *(const float4*)&a_w[dg];
    const float4 aw_s = *(const float4*)&a_w[DOUT + dg];
#pragma unroll
    for (int i = 0; i < 8; ++i) {
        int gn = row0 + r0 + i;
        float4 o;
        o.x = acc[i][0] + bb.x;
        o.y = acc[i][1] + bb.y;
        o.z = acc[i][2] + bb.z;
        o.w = acc[i][3] + bb.w;
        if (gn < N) {
            ushort4 hb;
            hb.x = f2bf(o.x); hb.y = f2bf(o.y); hb.z = f2bf(o.z); hb.w = f2bf(o.w);
            *(ushort4*)&h[(size_t)gn * DOUT + dg] = hb;
        }
        float sd = o.x * aw_d.x + o.y * aw_d.y + o.z * aw_d.z + o.w * aw_d.w;
        float ss = o.x * aw_s.x + o.y * aw_s.y + o.z * aw_s.z + o.w * aw_s.w;
#pragma unroll
        for (int off = 16; off; off >>= 1) {
            sd += __shfl_xor(sd, off, 32);
            ss += __shfl_xor(ss, off, 32);
        }
        if ((tid & 31) == 0 && gn < N) { s_dst[gn] = sd; s_src[gn] = ss; }
    }
}

// ---------------- segment softmax + aggregation: 16-lane group per node ----------------
// Single fused softmax pass (no max-subtraction: logits ~ N(0,1), exp safe).
// Pass 2 keeps 8 uint4 row-loads in flight per lane against L2/L3 latency.
#define GL 16      // lanes per group
#define KSLOT 4    // register slots -> 64 edges cached

__device__ __forceinline__ void fma8(unsigned int u0, unsigned int u1,
                                     unsigned int u2, unsigned int u3,
                                     float w, float* a) {
    union { unsigned int i; float f; } c;
    c.i = u0 << 16;         a[0] += w * c.f;
    c.i = u0 & 0xFFFF0000u; a[1] += w * c.f;
    c.i = u1 << 16;         a[2] += w * c.f;
    c.i = u1 & 0xFFFF0000u; a[3] += w * c.f;
    c.i = u2 << 16;         a[4] += w * c.f;
    c.i = u2 & 0xFFFF0000u; a[5] += w * c.f;
    c.i = u3 << 16;         a[6] += w * c.f;
    c.i = u3 & 0xFFFF0000u; a[7] += w * c.f;
}

__global__ __launch_bounds__(256)
void gat_agg(const int* __restrict__ edge_src, const int* __restrict__ offsets,
             const unsigned short* __restrict__ h, const float* __restrict__ s_src,
             const float* __restrict__ s_dst, const float* __restrict__ a_b,
             float* __restrict__ out, int N)
{
    const int lg16 = threadIdx.x & (GL - 1);            // lane within group
    const int n = blockIdx.x * 16 + (threadIdx.x >> 4); // node for this group
    const bool active = (n < N);

    int start = 0, end = 0;
    float sdn = 0.f;
    if (active) {
        start = offsets[n];
        end = offsets[n + 1];
        sdn = s_dst[n] + a_b[0];
    }
    const int deg = end - start;

    // ---- pass 1 (fused): exp weights into register slots + group sum ----
    float wr[KSLOT];
    int   sreg[KSLOT];
    float mysum = 0.f;
#pragma unroll
    for (int t = 0; t < KSLOT; ++t) {
        int i = lg16 + t * GL;
        wr[t] = 0.f; sreg[t] = 0;
        if (i < deg) {
            int s = edge_src[start + i];
            float lg = sdn + s_src[s];
            lg = lg >= 0.f ? lg : NEG * lg;
            float w = __expf(lg);
            sreg[t] = s; wr[t] = w;
            mysum += w;
        }
    }
    for (int i = lg16 + KSLOT * GL; i < deg; i += GL) {  // overflow (deg>64, ~never)
        float lg = sdn + s_src[edge_src[start + i]];
        lg = lg >= 0.f ? lg : NEG * lg;
        mysum += __expf(lg);
    }
#pragma unroll
    for (int o = 8; o; o >>= 1) mysum += __shfl_xor(mysum, o, GL);

    // ---- pass 2: gather rows; lane = 8 dims (16 lanes x 16B = 256B bf16 row) ----
    const uint4* __restrict__ h4 = (const uint4*)h;      // row stride = 16 uint4
    float a[8];
#pragma unroll
    for (int q = 0; q < 8; ++q) a[q] = 0.f;

    const int degc = deg < KSLOT * GL ? deg : KSLOT * GL;
#pragma unroll
    for (int t = 0; t < KSLOT; ++t) {
        const int base = t * GL;
        if (base >= degc) break;
        const int cnt = (degc - base) < GL ? (degc - base) : GL;
        const float wt = wr[t];
        const int   st = sreg[t];
        int j = 0;
        for (; j + 8 <= cnt; j += 8) {                   // 8 rows in flight
            float wj[8]; int sj[8]; uint4 vj[8];
#pragma unroll
            for (int q = 0; q < 8; ++q) {
                wj[q] = __shfl(wt, j + q, GL);
                sj[q] = __shfl(st, j + q, GL);
            }
#pragma unroll
            for (int q = 0; q < 8; ++q) vj[q] = h4[(size_t)sj[q] * 16 + lg16];
#pragma unroll
            for (int q = 0; q < 8; ++q) fma8(vj[q].x, vj[q].y, vj[q].z, vj[q].w, wj[q], a);
        }
        for (; j < cnt; ++j) {
            float w = __shfl(wt, j, GL); int s = __shfl(st, j, GL);
            uint4 v = h4[(size_t)s * 16 + lg16];
            fma8(v.x, v.y, v.z, v.w, w, a);
        }
    }
    for (int i = KSLOT * GL; i < deg; ++i) {             // overflow (uniform addr)
        int s = edge_src[start + i];
        float lgv = sdn + s_src[s];
        lgv = lgv >= 0.f ? lgv : NEG * lgv;
        float w = __expf(lgv);
        uint4 v = h4[(size_t)s * 16 + lg16];
        fma8(v.x, v.y, v.z, v.w, w, a);
    }

    if (active) {
        const float inv = 1.f / fmaxf(mysum, 1e-16f);
        float4 o0, o1;
        o0.x = a[0] * inv; o0.y = a[1] * inv; o0.z = a[2] * inv; o0.w = a[3] * inv;
        o1.x = a[4] * inv; o1.y = a[5] * inv; o1.z = a[6] * inv; o1.w = a[7] * inv;
        float4* op = (float4*)&out[(size_t)n * DOUT + lg16 * 8];
        op[0] = o0;
        op[1] = o1;
    }
}

extern "C" void kernel_launch(void* const* d_in, const int* in_sizes, int n_in,
                              void* d_out, int out_size, void* d_ws, size_t ws_size,
                              hipStream_t stream)
{
    const float* x        = (const float*)d_in[0];
    const int*   edge_src = (const int*)d_in[1];
    const int*   edge_dst = (const int*)d_in[2];
    const float* W        = (const float*)d_in[3];
    const float* b        = (const float*)d_in[4];
    const float* a_w      = (const float*)d_in[5];
    const float* a_b      = (const float*)d_in[6];
    const int N = in_sizes[0] / DOUT;
    const int E = in_sizes[1];
    float* out = (float*)d_out;

    char* ws = (char*)d_ws;
    unsigned short* h = (unsigned short*)ws;  ws += (size_t)N * DOUT * sizeof(unsigned short);
    float* s_dst   = (float*)ws;  ws += (size_t)N * sizeof(float);
    float* s_src   = (float*)ws;  ws += (size_t)N * sizeof(float);
    int*   offsets = (int*)ws;    ws += (size_t)(N + 1) * sizeof(int);

    const int gemmBlocks = (N + BM - 1) / BM;
    const int buildBlocks = (E + 255) / 256;
    gemm_build<<<gemmBlocks + buildBlocks, 256, 0, stream>>>(
        x, W, b, a_w, h, s_dst, s_src, edge_dst, offsets, N, E, gemmBlocks);
    gat_agg<<<(N + 15) / 16, 256, 0, stream>>>(edge_src, offsets, h, s_src, s_dst, a_b, out, N);
}

// Round 10
// 146.615 us; speedup vs baseline: 1.0788x; 1.0750x over previous
//
#include <hip/hip_runtime.h>
#include <hip/hip_bf16.h>

#define DOUT 128
#define NEG 0.01f

typedef __attribute__((ext_vector_type(8))) short bf16x8;   // 8 bf16 = 4 VGPRs
typedef __attribute__((ext_vector_type(4))) float f32x4;

__device__ __forceinline__ unsigned short f2bf(float f) {
    union { float f; unsigned int i; } c; c.f = f;
    unsigned int r = c.i + 0x7FFF + ((c.i >> 16) & 1);   // round-to-nearest-even
    return (unsigned short)(r >> 16);
}

// ---------------- prep: Wt = bf16(W^T) [dim][k] | CSR offsets ----------------
// Blocks [0,64): transpose+convert W (64KB, L1/L2-hot; coalesced reads,
// scattered 2B writes - tiny). Blocks beyond: CSR offsets from sorted edge_dst.
__global__ __launch_bounds__(256)
void prep_build(const float* __restrict__ W, unsigned short* __restrict__ Wt,
                const int* __restrict__ edge_dst, int* __restrict__ offsets,
                int N, int E)
{
    const int tid = threadIdx.x;
    if (blockIdx.x < 64) {
        int idx = blockIdx.x * 256 + tid;     // 0..16383
        int k = idx >> 7;                     // W row
        int d = idx & 127;                    // W col (coalesced read over d)
        Wt[(size_t)d * 128 + k] = f2bf(W[(size_t)k * 128 + d]);
        return;
    }
    int e = (blockIdx.x - 64) * 256 + tid;
    if (e < E) {
        int dd = edge_dst[e];
        int prev = (e == 0) ? -1 : edge_dst[e - 1];
        for (int n = prev + 1; n <= dd; ++n) offsets[n] = e;
        if (e == E - 1)
            for (int n = dd + 1; n <= N; ++n) offsets[n] = E;
    }
}

// ---------------- MFMA GEMM: h = bf16(x@W+b), fused s_dst/s_src ----------------
// Wave = 16 nodes x 128 dims; 4 waves/block -> 64 nodes/block. A-frags
// converted in-register from coalesced fp32 x reads (each inst covers 16 rows
// x 128B contiguous). B-frags: per-lane 16B loads from Wt (32KB, L1-resident
// after first touch). No LDS, no barriers. C-layout: col=lane&15,
// row=(lane>>4)*4+reg (guide-verified).
__global__ __launch_bounds__(256)
void gemm_mfma(const float* __restrict__ x, const unsigned short* __restrict__ Wt,
               const float* __restrict__ b, const float* __restrict__ a_w,
               unsigned short* __restrict__ h, float* __restrict__ s_dst,
               float* __restrict__ s_src, int N)
{
    const int lane = threadIdx.x & 63;
    const int wave = threadIdx.x >> 6;
    const int m = lane & 15;              // A row / C col index
    const int q = lane >> 4;              // quad
    const int r0 = blockIdx.x * 64 + wave * 16;
    const int rowm = r0 + m;
    const int rowl = rowm < N ? rowm : N - 1;   // clamp loads; stores predicated

    // A-frags: lane holds x[rowm][s*32 + q*8 .. +8] as bf16, per k-slab s
    bf16x8 a[4];
    const float* xr = x + (size_t)rowl * 128;
#pragma unroll
    for (int s = 0; s < 4; ++s) {
        float4 p0 = *(const float4*)&xr[s * 32 + q * 8];
        float4 p1 = *(const float4*)&xr[s * 32 + q * 8 + 4];
        bf16x8 t;
        t[0] = (short)f2bf(p0.x); t[1] = (short)f2bf(p0.y);
        t[2] = (short)f2bf(p0.z); t[3] = (short)f2bf(p0.w);
        t[4] = (short)f2bf(p1.x); t[5] = (short)f2bf(p1.y);
        t[6] = (short)f2bf(p1.z); t[7] = (short)f2bf(p1.w);
        a[s] = t;
    }

    float sd[4] = {0.f, 0.f, 0.f, 0.f};
    float ss[4] = {0.f, 0.f, 0.f, 0.f};
    const int rq0 = r0 + q * 4;           // C rows this lane holds: rq0+reg

#pragma unroll 1                          // unrolling d would blow VGPRs (R3 lesson)
    for (int d = 0; d < 8; ++d) {
        const int col = d * 16 + m;       // output dim
        bf16x8 bfr[4];
#pragma unroll
        for (int s = 0; s < 4; ++s)
            bfr[s] = *(const bf16x8*)&Wt[(size_t)col * 128 + s * 32 + q * 8];
        f32x4 acc = {0.f, 0.f, 0.f, 0.f};
#pragma unroll
        for (int s = 0; s < 4; ++s)
            acc = __builtin_amdgcn_mfma_f32_16x16x32_bf16(a[s], bfr[s], acc, 0, 0, 0);
        const float bb  = b[col];
        const float awd = a_w[col];
        const float aws = a_w[DOUT + col];
#pragma unroll
        for (int reg = 0; reg < 4; ++reg) {
            float o = acc[reg] + bb;
            int row = rq0 + reg;
            if (row < N) h[(size_t)row * 128 + col] = f2bf(o);
            sd[reg] += o * awd;
            ss[reg] += o * aws;
        }
    }

    // reduce s over the 16 col-lanes (same quad group holds same rows)
#pragma unroll
    for (int reg = 0; reg < 4; ++reg) {
#pragma unroll
        for (int o = 8; o; o >>= 1) {
            sd[reg] += __shfl_xor(sd[reg], o, 16);
            ss[reg] += __shfl_xor(ss[reg], o, 16);
        }
    }
    if (m == 0) {
#pragma unroll
        for (int reg = 0; reg < 4; ++reg) {
            int row = rq0 + reg;
            if (row < N) { s_dst[row] = sd[reg]; s_src[row] = ss[reg]; }
        }
    }
}

// ---------------- segment softmax + aggregation: 16-lane group per node ----------------
// Single fused softmax pass (no max-subtraction: logits ~ N(0,1), exp safe).
// Pass 2 keeps 8 uint4 row-loads in flight per lane against L2/L3 latency.
#define GL 16      // lanes per group
#define KSLOT 4    // register slots -> 64 edges cached

__device__ __forceinline__ void fma8(unsigned int u0, unsigned int u1,
                                     unsigned int u2, unsigned int u3,
                                     float w, float* a) {
    union { unsigned int i; float f; } c;
    c.i = u0 << 16;         a[0] += w * c.f;
    c.i = u0 & 0xFFFF0000u; a[1] += w * c.f;
    c.i = u1 << 16;         a[2] += w * c.f;
    c.i = u1 & 0xFFFF0000u; a[3] += w * c.f;
    c.i = u2 << 16;         a[4] += w * c.f;
    c.i = u2 & 0xFFFF0000u; a[5] += w * c.f;
    c.i = u3 << 16;         a[6] += w * c.f;
    c.i = u3 & 0xFFFF0000u; a[7] += w * c.f;
}

__global__ __launch_bounds__(256)
void gat_agg(const int* __restrict__ edge_src, const int* __restrict__ offsets,
             const unsigned short* __restrict__ h, const float* __restrict__ s_src,
             const float* __restrict__ s_dst, const float* __restrict__ a_b,
             float* __restrict__ out, int N)
{
    const int lg16 = threadIdx.x & (GL - 1);            // lane within group
    const int n = blockIdx.x * 16 + (threadIdx.x >> 4); // node for this group
    const bool active = (n < N);

    int start = 0, end = 0;
    float sdn = 0.f;
    if (active) {
        start = offsets[n];
        end = offsets[n + 1];
        sdn = s_dst[n] + a_b[0];
    }
    const int deg = end - start;

    // ---- pass 1 (fused): exp weights into register slots + group sum ----
    float wr[KSLOT];
    int   sreg[KSLOT];
    float mysum = 0.f;
#pragma unroll
    for (int t = 0; t < KSLOT; ++t) {
        int i = lg16 + t * GL;
        wr[t] = 0.f; sreg[t] = 0;
        if (i < deg) {
            int s = edge_src[start + i];
            float lg = sdn + s_src[s];
            lg = lg >= 0.f ? lg : NEG * lg;
            float w = __expf(lg);
            sreg[t] = s; wr[t] = w;
            mysum += w;
        }
    }
    for (int i = lg16 + KSLOT * GL; i < deg; i += GL) {  // overflow (deg>64, ~never)
        float lg = sdn + s_src[edge_src[start + i]];
        lg = lg >= 0.f ? lg : NEG * lg;
        mysum += __expf(lg);
    }
#pragma unroll
    for (int o = 8; o; o >>= 1) mysum += __shfl_xor(mysum, o, GL);

    // ---- pass 2: gather rows; lane = 8 dims (16 lanes x 16B = 256B bf16 row) ----
    const uint4* __restrict__ h4 = (const uint4*)h;      // row stride = 16 uint4
    float a[8];
#pragma unroll
    for (int q = 0; q < 8; ++q) a[q] = 0.f;

    const int degc = deg < KSLOT * GL ? deg : KSLOT * GL;
#pragma unroll
    for (int t = 0; t < KSLOT; ++t) {
        const int base = t * GL;
        if (base >= degc) break;
        const int cnt = (degc - base) < GL ? (degc - base) : GL;
        const float wt = wr[t];
        const int   st = sreg[t];
        int j = 0;
        for (; j + 8 <= cnt; j += 8) {                   // 8 rows in flight
            float wj[8]; int sj[8]; uint4 vj[8];
#pragma unroll
            for (int q = 0; q < 8; ++q) {
                wj[q] = __shfl(wt, j + q, GL);
                sj[q] = __shfl(st, j + q, GL);
            }
#pragma unroll
            for (int q = 0; q < 8; ++q) vj[q] = h4[(size_t)sj[q] * 16 + lg16];
#pragma unroll
            for (int q = 0; q < 8; ++q) fma8(vj[q].x, vj[q].y, vj[q].z, vj[q].w, wj[q], a);
        }
        for (; j < cnt; ++j) {
            float w = __shfl(wt, j, GL); int s = __shfl(st, j, GL);
            uint4 v = h4[(size_t)s * 16 + lg16];
            fma8(v.x, v.y, v.z, v.w, w, a);
        }
    }
    for (int i = KSLOT * GL; i < deg; ++i) {             // overflow (uniform addr)
        int s = edge_src[start + i];
        float lgv = sdn + s_src[s];
        lgv = lgv >= 0.f ? lgv : NEG * lgv;
        float w = __expf(lgv);
        uint4 v = h4[(size_t)s * 16 + lg16];
        fma8(v.x, v.y, v.z, v.w, w, a);
    }

    if (active) {
        const float inv = 1.f / fmaxf(mysum, 1e-16f);
        float4 o0, o1;
        o0.x = a[0] * inv; o0.y = a[1] * inv; o0.z = a[2] * inv; o0.w = a[3] * inv;
        o1.x = a[4] * inv; o1.y = a[5] * inv; o1.z = a[6] * inv; o1.w = a[7] * inv;
        float4* op = (float4*)&out[(size_t)n * DOUT + lg16 * 8];
        op[0] = o0;
        op[1] = o1;
    }
}

extern "C" void kernel_launch(void* const* d_in, const int* in_sizes, int n_in,
                              void* d_out, int out_size, void* d_ws, size_t ws_size,
                              hipStream_t stream)
{
    const float* x        = (const float*)d_in[0];
    const int*   edge_src = (const int*)d_in[1];
    const int*   edge_dst = (const int*)d_in[2];
    const float* W        = (const float*)d_in[3];
    const float* b        = (const float*)d_in[4];
    const float* a_w      = (const float*)d_in[5];
    const float* a_b      = (const float*)d_in[6];
    const int N = in_sizes[0] / DOUT;
    const int E = in_sizes[1];
    float* out = (float*)d_out;

    char* ws = (char*)d_ws;
    unsigned short* h  = (unsigned short*)ws;  ws += (size_t)N * DOUT * sizeof(unsigned short);
    float* s_dst   = (float*)ws;  ws += (size_t)N * sizeof(float);
    float* s_src   = (float*)ws;  ws += (size_t)N * sizeof(float);
    int*   offsets = (int*)ws;    ws += (size_t)(N + 1) * sizeof(int);
    unsigned short* Wt = (unsigned short*)ws;  ws += (size_t)DOUT * DOUT * sizeof(unsigned short);

    const int buildBlocks = (E + 255) / 256;
    prep_build<<<64 + buildBlocks, 256, 0, stream>>>(W, Wt, edge_dst, offsets, N, E);
    gemm_mfma<<<(N + 63) / 64, 256, 0, stream>>>(x, Wt, b, a_w, h, s_dst, s_src, N);
    gat_agg<<<(N + 15) / 16, 256, 0, stream>>>(edge_src, offsets, h, s_src, s_dst, a_b, out, N);
}